// Round 18
// baseline (305.543 us; speedup 1.0000x reference)
//
#include <hip/hip_runtime.h>

typedef _Float16 f16;
typedef _Float16 f16x8 __attribute__((ext_vector_type(8)));
typedef _Float16 f16x4 __attribute__((ext_vector_type(4)));
typedef float f32x4 __attribute__((ext_vector_type(4)));
typedef unsigned int u32;
typedef unsigned int u32x4 __attribute__((ext_vector_type(4)));

#define MFMA16(a, b, c) __builtin_amdgcn_mfma_f32_16x16x32_f16(a, b, c, 0, 0, 0)

__device__ __forceinline__ void async_copy16(f16* lds, const f16* g) {
    __builtin_amdgcn_global_load_lds(
        (const __attribute__((address_space(1))) unsigned int*)g,
        (__attribute__((address_space(3))) unsigned int*)lds,
        16, 0, 0);
}

// ---------------------------------------------------------------- prep ----
// Weights/bias/tokmap only — x is consumed fp32 directly by qkv (the
// 159MB xh convert round-trip is gone).
__global__ __launch_bounds__(256) void prep_kernel(
    const float* __restrict__ Wq, const float* __restrict__ Wk,
    const float* __restrict__ Wv, const float* __restrict__ Wp,
    const float* __restrict__ bq, const float* __restrict__ bk,
    const float* __restrict__ bv,
    f16* __restrict__ Wqkv, f16* __restrict__ Wph, float* __restrict__ bqkv,
    int* __restrict__ tokmap)
{
    int i = blockIdx.x * 256 + threadIdx.x;
    if (i < 786432) {
        int r = i >> 9, c = i & 511;
        const float* src = (r < 512) ? Wq : (r < 1024) ? Wk : Wv;
        Wqkv[i] = (f16)src[(r & 511) * 512 + c];
    } else if (i < 786432 + 262144) {
        int j = i - 786432;
        Wph[j] = (f16)Wp[j];
    } else if (i < 786432 + 262144 + 1536) {
        int j = i - (786432 + 262144);
        bqkv[j] = (j < 512) ? bq[j] : (j < 1024) ? bk[j - 512] : bv[j - 1024];
    } else if (i < 786432 + 262144 + 1536 + 51840) {
        int j = i - (786432 + 262144 + 1536);
        int t_ = j / 6480, rem = j % 6480;
        int hh = rem / 108, ww = rem % 108;
        int win = (hh / 5) * 12 + (ww / 9);
        int s = t_ * 45 + (hh % 5) * 9 + (ww % 9);
        tokmap[j] = win * 1440 + s;   // obase/128 (head 0)
    }
}

// ------------------------------------------------------------ QKV GEMM ----
// 128x128, BK=32, ring-3 (48KB f16 -> 3 blocks/CU) — champion geometry.
// A: fp32 X read direct from HBM into REGISTERS one step ahead (2 banks),
//    cvt fp32->f16, conflict-free ds_write_b64 into the SAME swizzled f16
//    layout the champion reads (read path byte-identical).
// B: async global_load_lds as before.
// FIFO: cvt's auto-wait on A(t+1) drains B(t) (older); explicit
// vmcnt(6)+lgkmcnt(0) before raw barrier drains B(t+1) while
// A(t+2)[4]+B(t+2)[2] stay in flight. Tail t=14 -> vmcnt(0).
__global__ __launch_bounds__(256, 3) void qkv_gemm(
    const float* __restrict__ X, const f16* __restrict__ W,
    const float* __restrict__ bias, const int* __restrict__ tokmap,
    f16* __restrict__ Qp, f16* __restrict__ Kp, f16* __restrict__ Vp)
{
    __shared__ __align__(16) f16 As[3][128 * 32];
    __shared__ __align__(16) f16 Bs[3][128 * 32];
    const int tid = threadIdx.x;
    const int lane = tid & 63, wid = tid >> 6;
    const int g = lane >> 4, l15 = lane & 15;
    const int wr = wid >> 1, wc = wid & 1;

    // bijective XCD chunk remap (nwg=4860, q=607, r=4)
    const int orig = blockIdx.x;
    const int xcd = orig & 7;
    const int wg = (xcd < 4 ? xcd * 608 : 2432 + (xcd - 4) * 607) + (orig >> 3);
    const int bn = wg % 12;
    const int brow = (wg / 12) * 128;

    const float* Abase = X + (size_t)brow * 512;
    const f16* Bbase = W + (size_t)bn * 128 * 512;

    f32x4 acc[4][4] = {};
    f32x4 arA[4], arB[4];   // A reg banks (t even -> arA holds t+2, etc.)

    // A reg-load: item idx=(rr*256+tid): row=idx>>3, fp32-slot=idx&7 (16B).
    // Coalesced: 8 consecutive lanes cover one 128B row-segment.
    #define LOAD_A(bank, step)                                                \
        {                                                                     \
            _Pragma("unroll")                                                 \
            for (int rr = 0; rr < 4; ++rr) {                                  \
                int idx = rr * 256 + tid;                                     \
                int row = idx >> 3, s = idx & 7;                              \
                bank[rr] = *(const f32x4*)(Abase + (size_t)row * 512 +        \
                                           (step) * 32 + s * 4);              \
            }                                                                 \
        }

    // cvt + swizzled ds_write_b64: fp32-slot s -> f16-slot fs=s>>1, half
    // s&1; physical slot ws = fs ^ ((row>>1)&3) == champion's read XOR.
    // Bank check: 16-lane group = 2 full rows (32 dw) -> conflict-free.
    #define CVT_WRITE(bank, step)                                             \
        {                                                                     \
            _Pragma("unroll")                                                 \
            for (int rr = 0; rr < 4; ++rr) {                                  \
                int idx = rr * 256 + tid;                                     \
                int row = idx >> 3, s = idx & 7;                              \
                int ws = (s >> 1) ^ ((row >> 1) & 3);                         \
                f32x4 v = bank[rr];                                           \
                f16x4 h = { (f16)v[0], (f16)v[1], (f16)v[2], (f16)v[3] };     \
                *(f16x4*)&As[(step) % 3][row * 32 + ws * 8 + (s & 1) * 4] = h;\
            }                                                                 \
        }

    #define LOAD_B(step)                                                      \
        {                                                                     \
            const int k0_ = (step) * 32;                                      \
            _Pragma("unroll")                                                 \
            for (int rr = 0; rr < 2; ++rr) {                                  \
                int idx = rr * 256 + tid;                                     \
                int row = idx >> 2, ch = idx & 3;                             \
                int sch = ch ^ ((row >> 1) & 3);                              \
                async_copy16(&Bs[(step) % 3][idx * 8],                        \
                             Bbase + (size_t)row * 512 + k0_ + sch * 8);      \
            }                                                                 \
        }

    // one K-step: frag reads + MFMA on 'cur'; prefetch t+2; write A(t+1)
    #define GEMM_STEP(t_, BCUR, BNXT)                                         \
        {                                                                     \
            const int cur = (t_) % 3;                                         \
            f16x8 a[4], b[4];                                                 \
            _Pragma("unroll")                                                 \
            for (int m = 0; m < 4; ++m) {                                     \
                int arow = wr * 64 + m * 16 + l15;                            \
                int sl = g ^ ((arow >> 1) & 3);                               \
                a[m] = *(const f16x8*)&As[cur][arow * 32 + sl * 8];           \
            }                                                                 \
            _Pragma("unroll")                                                 \
            for (int n = 0; n < 4; ++n) {                                     \
                int brw = wc * 64 + n * 16 + l15;                             \
                int sl = g ^ ((brw >> 1) & 3);                                \
                b[n] = *(const f16x8*)&Bs[cur][brw * 32 + sl * 8];            \
            }                                                                 \
            if ((t_) + 2 < 16) { LOAD_A(BCUR, (t_) + 2); LOAD_B((t_) + 2); }  \
            if ((t_) + 1 < 16) { CVT_WRITE(BNXT, (t_) + 1); }                 \
            __builtin_amdgcn_s_setprio(1);                                    \
            _Pragma("unroll")                                                 \
            for (int m = 0; m < 4; ++m)                                       \
                _Pragma("unroll")                                             \
                for (int n = 0; n < 4; ++n)                                   \
                    acc[m][n] = MFMA16(a[m], b[n], acc[m][n]);                \
            __builtin_amdgcn_s_setprio(0);                                    \
            if ((t_) < 14)                                                    \
                asm volatile("s_waitcnt vmcnt(6) lgkmcnt(0)" ::: "memory");   \
            else if ((t_) == 14)                                              \
                asm volatile("s_waitcnt vmcnt(0) lgkmcnt(0)" ::: "memory");   \
            if ((t_) < 15) __builtin_amdgcn_s_barrier();                      \
        }

    // prologue: A(0)->arA, B(0); A(1)->arB, B(1); write A(0); gate B(0)
    LOAD_A(arA, 0); LOAD_B(0);
    LOAD_A(arB, 1); LOAD_B(1);
    CVT_WRITE(arA, 0);                         // auto-drains A(0)
    asm volatile("s_waitcnt vmcnt(6) lgkmcnt(0)" ::: "memory");  // B(0) done
    __builtin_amdgcn_s_barrier();

    #pragma unroll
    for (int tt = 0; tt < 8; ++tt) {
        GEMM_STEP(2 * tt,     arA, arB);       // cvt A(odd)  from arB
        GEMM_STEP(2 * tt + 1, arB, arA);       // cvt A(even) from arA
    }
    #undef GEMM_STEP
    #undef LOAD_B
    #undef CVT_WRITE
    #undef LOAD_A

    // epilogue: C/D layout col = lane&15, row = (lane>>4)*4 + reg
    const int which = bn >> 2, head = bn & 3;
    f16* dst = (which == 0) ? Qp : (which == 1) ? Kp : Vp;
    #pragma unroll
    for (int m = 0; m < 4; ++m) {
        #pragma unroll
        for (int j = 0; j < 4; ++j) {
            int gm = brow + wr * 64 + m * 16 + g * 4 + j;  // token index
            size_t obase = ((size_t)(tokmap[gm] + head * 360)) * 128;
            #pragma unroll
            for (int n = 0; n < 4; ++n) {
                int cidx = wc * 64 + n * 16 + l15;
                float v = acc[m][n][j] + bias[bn * 128 + cidx];
                dst[obase + cidx] = (f16)v;
            }
        }
    }
}

// ----------------------------------------------------------- attention ----
// r17 version: async double-buffered K (gload_lds, XOR swizzle), V
// register-repack, max-free softmax, XCD-chunked grid swizzle,
// conflict-free strides (Vt 76, Pl 68).
__global__ __launch_bounds__(256, 2) void attn_kernel(
    const f16* __restrict__ Qp, const f16* __restrict__ Kp,
    const f16* __restrict__ Vp, f16* __restrict__ AO)
{
    __shared__ __align__(128) f16 Kl[2][64 * 128];
    __shared__ __align__(16)  f16 Vt[128 * 76];
    __shared__ __align__(16)  f16 Pl[192 * 68];

    const int tid = threadIdx.x;
    const int lane = tid & 63, wid = tid >> 6;      // wid 0..3
    const int g = lane >> 4, l15 = lane & 15;
    const int orig = blockIdx.x;
    const int bid = (orig & 7) * 144 + (orig >> 3); // XCD-chunked remap
    const int wh = bid >> 1;                        // win*4+head
    const int half = bid & 1;
    const int win = wh >> 2, head = wh & 3;
    const int base = wh * 46080;                    // 360*128
    const int qbase = half * 192 + wid * 48;        // this wave's first q-row

    const float SC2 = 0.08838834764831845f * 1.4426950408889634f;  // scale*log2e

    #define STAGE_K(buf, kt_)                                                 \
        {                                                                     \
            _Pragma("unroll")                                                 \
            for (int it = 0; it < 4; ++it) {                                  \
                int chunk = it * 256 + tid;                                   \
                int krow = chunk >> 4, c = chunk & 15;                        \
                int sc_ = c ^ (krow & 7);                                     \
                async_copy16(&Kl[buf][chunk * 8],                             \
                    Kp + base + (size_t)((kt_) * 64 + krow) * 128 + sc_ * 8); \
            }                                                                 \
        }

    f16x8 qf[3][4];
    #pragma unroll
    for (int qi = 0; qi < 3; ++qi)
        #pragma unroll
        for (int c4 = 0; c4 < 4; ++c4)
            qf[qi][c4] = *(const f16x8*)(Qp + base + (qbase + qi * 16 + l15) * 128 + c4 * 32 + g * 8);

    STAGE_K(0, 0);

    f32x4 o[3][8] = {};
    float l_r[3] = { 0.f, 0.f, 0.f };

    for (int kt = 0; kt < 6; ++kt) {
        const int cb = kt & 1;
        // --- stage V tile transposed: [ch][k], zero-fill k >= 360, 256 thr
        #pragma unroll
        for (int it = 0; it < 2; ++it) {
            int i2 = it * 256 + tid;
            int kb = i2 >> 6;
            int chp = (i2 & 63) * 2;
            const u32* Vb = (const u32*)(Vp + base);
            u32 d[8];
            #pragma unroll
            for (int i = 0; i < 8; ++i) {
                int kg = kt * 64 + kb * 8 + i;
                d[i] = (kg < 360) ? Vb[kg * 64 + (chp >> 1)] : 0u;
            }
            u32x4 lo, hi;
            #pragma unroll
            for (int jj = 0; jj < 4; ++jj) {
                lo[jj] = (d[2 * jj] & 0xffffu) | (d[2 * jj + 1] << 16);
                hi[jj] = (d[2 * jj] >> 16) | (d[2 * jj + 1] & 0xffff0000u);
            }
            *(u32x4*)&Vt[chp * 76 + kb * 8] = lo;
            *(u32x4*)&Vt[(chp + 1) * 76 + kb * 8] = hi;
        }
        __syncthreads();
        if (kt + 1 < 6) STAGE_K(cb ^ 1, kt + 1);

        // --- S^T = K · Q^T : C[k,q], lane holds col q=lane&15, rows k=g*4+j
        f32x4 sc[4][3] = {};
        __builtin_amdgcn_s_setprio(1);
        #pragma unroll
        for (int c4 = 0; c4 < 4; ++c4) {
            f16x8 ka[4];
            #pragma unroll
            for (int kf = 0; kf < 4; ++kf) {
                int row = kf * 16 + l15;
                int sl = (c4 * 4 + g) ^ (row & 7);
                ka[kf] = *(const f16x8*)&Kl[cb][row * 128 + sl * 8];
            }
            #pragma unroll
            for (int kf = 0; kf < 4; ++kf)
                #pragma unroll
                for (int qi = 0; qi < 3; ++qi)
                    sc[kf][qi] = MFMA16(ka[kf], qf[qi][c4], sc[kf][qi]);
        }
        __builtin_amdgcn_s_setprio(0);
        if (kt == 5) {
            #pragma unroll
            for (int kf = 0; kf < 4; ++kf)
                #pragma unroll
                for (int j = 0; j < 4; ++j)
                    if (320 + kf * 16 + g * 4 + j >= 360) {
                        #pragma unroll
                        for (int qi = 0; qi < 3; ++qi) sc[kf][qi][j] = -1e30f;
                    }
        }

        // --- max-free softmax: P = exp2(s*SC2); P -> LDS (rows wave-private)
        #pragma unroll
        for (int qi = 0; qi < 3; ++qi) {
            float psum = 0.f;
            #pragma unroll
            for (int kf = 0; kf < 4; ++kf) {
                f16x4 pv;
                #pragma unroll
                for (int j = 0; j < 4; ++j) {
                    float p = exp2f(sc[kf][qi][j] * SC2);
                    psum += p;
                    pv[j] = (f16)p;
                }
                *(f16x4*)&Pl[(wid * 48 + qi * 16 + l15) * 68 + kf * 16 + g * 4] = pv;
            }
            psum += __shfl_xor(psum, 16);
            psum += __shfl_xor(psum, 32);
            l_r[qi] += psum;
        }

        // --- PV: O[q,ch] += P[q,k] * V[k,ch]
        __builtin_amdgcn_s_setprio(1);
        #pragma unroll
        for (int kc = 0; kc < 2; ++kc) {
            f16x8 pa[3], vb[8];
            #pragma unroll
            for (int qi = 0; qi < 3; ++qi)
                pa[qi] = *(const f16x8*)&Pl[(wid * 48 + qi * 16 + l15) * 68 + kc * 32 + g * 8];
            #pragma unroll
            for (int chf = 0; chf < 8; ++chf)
                vb[chf] = *(const f16x8*)&Vt[(chf * 16 + l15) * 76 + kc * 32 + g * 8];
            #pragma unroll
            for (int qi = 0; qi < 3; ++qi)
                #pragma unroll
                for (int chf = 0; chf < 8; ++chf)
                    o[qi][chf] = MFMA16(pa[qi], vb[chf], o[qi][chf]);
        }
        __builtin_amdgcn_s_setprio(0);
        __syncthreads();
    }
    #undef STAGE_K

    // --- epilogue: normalize, un-partition, store fp16 AO[token][512]
    #pragma unroll
    for (int qi = 0; qi < 3; ++qi) {
        #pragma unroll
        for (int j = 0; j < 4; ++j) {
            float lj = __shfl(l_r[qi], g * 4 + j);
            float inv = 1.0f / lj;
            int s = qbase + qi * 16 + g * 4 + j;
            if (s < 360) {
                int t_ = s / 45, s45 = s % 45;
                int hh = (win / 12) * 5 + s45 / 9;
                int ww = (win % 12) * 9 + s45 % 9;
                int mm = t_ * 6480 + hh * 108 + ww;
                #pragma unroll
                for (int chf = 0; chf < 8; ++chf) {
                    int col = head * 128 + chf * 16 + l15;
                    AO[(size_t)mm * 512 + col] = (f16)(o[qi][chf][j] * inv);
                }
            }
        }
    }
}

// ----------------------------------------------------------- out proj ----
// 3-deep ring, BK=32, counted vmcnt(4). (champion version)
__global__ __launch_bounds__(256, 3) void proj_gemm(
    const f16* __restrict__ A, const f16* __restrict__ W,
    const float* __restrict__ bias, float* __restrict__ out)
{
    __shared__ __align__(16) f16 As[3][128 * 32];
    __shared__ __align__(16) f16 Bs[3][128 * 32];
    const int tid = threadIdx.x;
    const int lane = tid & 63, wid = tid >> 6;
    const int g = lane >> 4, l15 = lane & 15;
    const int wr = wid >> 1, wc = wid & 1;

    const int orig = blockIdx.x;
    const int xcd = orig & 7;
    const int wg = (xcd < 4 ? xcd * 203 : 812 + (xcd - 4) * 202) + (orig >> 3);
    const int bcol = (wg & 3) * 128;
    const int brow = (wg >> 2) * 128;

    const f16* Abase = A + (size_t)brow * 512;
    const f16* Bbase = W + (size_t)bcol * 512;

    f32x4 acc[4][4] = {};

    #define PROJ_STAGE(buf, step)                                             \
        {                                                                     \
            const int k0_ = (step) * 32;                                      \
            _Pragma("unroll")                                                 \
            for (int rr = 0; rr < 2; ++rr) {                                  \
                int idx = rr * 256 + tid;                                     \
                int row = idx >> 2, ch = idx & 3;                             \
                int sch = ch ^ ((row >> 1) & 3);                              \
                async_copy16(&As[buf][idx * 8],                               \
                             Abase + (size_t)row * 512 + k0_ + sch * 8);      \
                async_copy16(&Bs[buf][idx * 8],                               \
                             Bbase + (size_t)row * 512 + k0_ + sch * 8);      \
            }                                                                 \
        }

    PROJ_STAGE(0, 0);
    PROJ_STAGE(1, 1);

    int cur = 0;
    for (int t = 0; t < 16; ++t) {
        if (t < 15) asm volatile("s_waitcnt vmcnt(4)" ::: "memory");
        else        asm volatile("s_waitcnt vmcnt(0)" ::: "memory");
        __builtin_amdgcn_s_barrier();
        __builtin_amdgcn_sched_barrier(0);
        if (t + 2 < 16) {
            int stg = cur + 2; if (stg >= 3) stg -= 3;
            PROJ_STAGE(stg, t + 2);
        }
        f16x8 a[4], b[4];
        #pragma unroll
        for (int m = 0; m < 4; ++m) {
            int arow = wr * 64 + m * 16 + l15;
            int sl = g ^ ((arow >> 1) & 3);
            a[m] = *(const f16x8*)&As[cur][arow * 32 + sl * 8];
        }
        #pragma unroll
        for (int n = 0; n < 4; ++n) {
            int brw = wc * 64 + n * 16 + l15;
            int sl = g ^ ((brw >> 1) & 3);
            b[n] = *(const f16x8*)&Bs[cur][brw * 32 + sl * 8];
        }
        __builtin_amdgcn_s_setprio(1);
        #pragma unroll
        for (int m = 0; m < 4; ++m)
            #pragma unroll
            for (int n = 0; n < 4; ++n)
                acc[m][n] = MFMA16(a[m], b[n], acc[m][n]);
        __builtin_amdgcn_s_setprio(0);
        __builtin_amdgcn_s_barrier();
        cur = (cur == 2) ? 0 : cur + 1;
    }
    #undef PROJ_STAGE

    #pragma unroll
    for (int m = 0; m < 4; ++m)
        #pragma unroll
        for (int j = 0; j < 4; ++j) {
            int gm = brow + wr * 64 + m * 16 + g * 4 + j;
            #pragma unroll
            for (int n = 0; n < 4; ++n) {
                int gn = bcol + wc * 64 + n * 16 + l15;
                out[(size_t)gm * 512 + gn] = acc[m][n][j] + bias[gn];
            }
        }
}

// -------------------------------------------------------------- launch ----
extern "C" void kernel_launch(void* const* d_in, const int* in_sizes, int n_in,
                              void* d_out, int out_size, void* d_ws, size_t ws_size,
                              hipStream_t stream)
{
    (void)in_sizes; (void)n_in; (void)out_size; (void)ws_size;
    const float* x  = (const float*)d_in[0];
    const float* Wq = (const float*)d_in[1];
    const float* bq = (const float*)d_in[2];
    const float* Wk = (const float*)d_in[3];
    const float* bk = (const float*)d_in[4];
    const float* Wv = (const float*)d_in[5];
    const float* bv = (const float*)d_in[6];
    const float* Wp = (const float*)d_in[7];
    const float* bp = (const float*)d_in[8];

    // workspace layout (fp16 elems): Qp/Kp/Vp [576][360][128], AO [51840][512]
    f16* Qp   = (f16*)d_ws;
    f16* Kp   = Qp + 26542080;
    f16* Vp   = Kp + 26542080;
    f16* AO   = Vp + 26542080;
    f16* Wqkv = AO + 26542080;
    f16* Wph  = Wqkv + 786432;
    float* bqkv = (float*)(Wph + 262144);
    int* tokmap = (int*)(bqkv + 1536);

    prep_kernel<<<4305, 256, 0, stream>>>(Wq, Wk, Wv, Wp, bq, bk, bv,
                                          Wqkv, Wph, bqkv, tokmap);
    qkv_gemm<<<4860, 256, 0, stream>>>(x, Wqkv, bqkv, tokmap, Qp, Kp, Vp);
    attn_kernel<<<1152, 256, 0, stream>>>(Qp, Kp, Vp, AO);
    proj_gemm<<<1620, 256, 0, stream>>>(AO, Wph, bp, (float*)d_out);
}

// Round 19
// 261.478 us; speedup vs baseline: 1.1685x; 1.1685x over previous
//
#include <hip/hip_runtime.h>

typedef _Float16 f16;
typedef _Float16 f16x8 __attribute__((ext_vector_type(8)));
typedef _Float16 f16x4 __attribute__((ext_vector_type(4)));
typedef float f32x4 __attribute__((ext_vector_type(4)));
typedef unsigned int u32;
typedef unsigned int u32x4 __attribute__((ext_vector_type(4)));

#define MFMA16(a, b, c) __builtin_amdgcn_mfma_f32_16x16x32_f16(a, b, c, 0, 0, 0)

__device__ __forceinline__ void async_copy16(f16* lds, const f16* g) {
    __builtin_amdgcn_global_load_lds(
        (const __attribute__((address_space(1))) unsigned int*)g,
        (__attribute__((address_space(3))) unsigned int*)lds,
        16, 0, 0);
}

// -------------------------------------------------- prep + convert x ----
__global__ __launch_bounds__(256) void prep_convert(
    const float* __restrict__ x, f16* __restrict__ xh,
    const float* __restrict__ Wq, const float* __restrict__ Wk,
    const float* __restrict__ Wv, const float* __restrict__ Wp,
    const float* __restrict__ bq, const float* __restrict__ bk,
    const float* __restrict__ bv,
    f16* __restrict__ Wqkv, f16* __restrict__ Wph, float* __restrict__ bqkv,
    int* __restrict__ tokmap)
{
    if (blockIdx.x < 12960) {
        int i = blockIdx.x * 256 + threadIdx.x;
        f32x4 a = *(const f32x4*)(x + (size_t)i * 8);
        f32x4 b = *(const f32x4*)(x + (size_t)i * 8 + 4);
        f16x8 h = { (f16)a[0], (f16)a[1], (f16)a[2], (f16)a[3],
                    (f16)b[0], (f16)b[1], (f16)b[2], (f16)b[3] };
        *(f16x8*)(xh + (size_t)i * 8) = h;
        return;
    }
    int i = (blockIdx.x - 12960) * 256 + threadIdx.x;
    if (i < 786432) {
        int r = i >> 9, c = i & 511;
        const float* src = (r < 512) ? Wq : (r < 1024) ? Wk : Wv;
        Wqkv[i] = (f16)src[(r & 511) * 512 + c];
    } else if (i < 786432 + 262144) {
        int j = i - 786432;
        Wph[j] = (f16)Wp[j];
    } else if (i < 786432 + 262144 + 1536) {
        int j = i - (786432 + 262144);
        bqkv[j] = (j < 512) ? bq[j] : (j < 1024) ? bk[j - 512] : bv[j - 1024];
    } else if (i < 786432 + 262144 + 1536 + 51840) {
        int j = i - (786432 + 262144 + 1536);
        int t_ = j / 6480, rem = j % 6480;
        int hh = rem / 108, ww = rem % 108;
        int win = (hh / 5) * 12 + (ww / 9);
        int s = t_ * 45 + (hh % 5) * 9 + (ww % 9);
        tokmap[j] = win * 1440 + s;   // obase/128 (head 0)
    }
}

// ------------------------------------------------------------ QKV GEMM ----
// 128x128 tile, BK=32, 3-deep LDS ring (48KB -> 3 blocks/CU), counted
// vmcnt(4). Confirmed optimum for this K=512 shape (8 structural
// alternatives all regressed).
__global__ __launch_bounds__(256, 3) void qkv_gemm(
    const f16* __restrict__ Xh, const f16* __restrict__ W,
    const float* __restrict__ bias, const int* __restrict__ tokmap,
    f16* __restrict__ Qp, f16* __restrict__ Kp, f16* __restrict__ Vp)
{
    __shared__ __align__(16) f16 As[3][128 * 32];
    __shared__ __align__(16) f16 Bs[3][128 * 32];
    const int tid = threadIdx.x;
    const int lane = tid & 63, wid = tid >> 6;
    const int g = lane >> 4, l15 = lane & 15;
    const int wr = wid >> 1, wc = wid & 1;

    const int orig = blockIdx.x;
    const int xcd = orig & 7;
    const int wg = (xcd < 4 ? xcd * 608 : 2432 + (xcd - 4) * 607) + (orig >> 3);
    const int bn = wg % 12;
    const int brow = (wg / 12) * 128;

    const f16* Abase = Xh + (size_t)brow * 512;
    const f16* Bbase = W + (size_t)bn * 128 * 512;

    f32x4 acc[4][4] = {};

    #define QKV_STAGE(buf, step)                                              \
        {                                                                     \
            const int k0_ = (step) * 32;                                      \
            _Pragma("unroll")                                                 \
            for (int rr = 0; rr < 2; ++rr) {                                  \
                int idx = rr * 256 + tid;                                     \
                int row = idx >> 2, ch = idx & 3;                             \
                int sch = ch ^ ((row >> 1) & 3);                              \
                async_copy16(&As[buf][idx * 8],                               \
                             Abase + (size_t)row * 512 + k0_ + sch * 8);      \
                async_copy16(&Bs[buf][idx * 8],                               \
                             Bbase + (size_t)row * 512 + k0_ + sch * 8);      \
            }                                                                 \
        }

    QKV_STAGE(0, 0);
    QKV_STAGE(1, 1);

    int cur = 0;
    for (int t = 0; t < 16; ++t) {
        if (t < 15) asm volatile("s_waitcnt vmcnt(4)" ::: "memory");
        else        asm volatile("s_waitcnt vmcnt(0)" ::: "memory");
        __builtin_amdgcn_s_barrier();
        __builtin_amdgcn_sched_barrier(0);
        if (t + 2 < 16) {
            int stg = cur + 2; if (stg >= 3) stg -= 3;
            QKV_STAGE(stg, t + 2);
        }
        f16x8 a[4], b[4];
        #pragma unroll
        for (int m = 0; m < 4; ++m) {
            int arow = wr * 64 + m * 16 + l15;
            int sl = g ^ ((arow >> 1) & 3);
            a[m] = *(const f16x8*)&As[cur][arow * 32 + sl * 8];
        }
        #pragma unroll
        for (int n = 0; n < 4; ++n) {
            int brw = wc * 64 + n * 16 + l15;
            int sl = g ^ ((brw >> 1) & 3);
            b[n] = *(const f16x8*)&Bs[cur][brw * 32 + sl * 8];
        }
        __builtin_amdgcn_s_setprio(1);
        #pragma unroll
        for (int m = 0; m < 4; ++m)
            #pragma unroll
            for (int n = 0; n < 4; ++n)
                acc[m][n] = MFMA16(a[m], b[n], acc[m][n]);
        __builtin_amdgcn_s_setprio(0);
        __builtin_amdgcn_s_barrier();
        cur = (cur == 2) ? 0 : cur + 1;
    }
    #undef QKV_STAGE

    const int which = bn >> 2, head = bn & 3;
    f16* dst = (which == 0) ? Qp : (which == 1) ? Kp : Vp;
    #pragma unroll
    for (int m = 0; m < 4; ++m) {
        #pragma unroll
        for (int j = 0; j < 4; ++j) {
            int gm = brow + wr * 64 + m * 16 + g * 4 + j;  // token index
            size_t obase = ((size_t)(tokmap[gm] + head * 360)) * 128;
            #pragma unroll
            for (int n = 0; n < 4; ++n) {
                int cidx = wc * 64 + n * 16 + l15;
                float v = acc[m][n][j] + bias[bn * 128 + cidx];
                dst[obase + cidx] = (f16)v;
            }
        }
    }
}

// ----------------------------------------------------------- attention ----
// Async double-buffered K (gload_lds, XOR swizzle) prefetched across the
// compute phase; V register-repack; max-free softmax; XCD-chunked grid
// swizzle; conflict-free strides (Vt 76, Pl 68). LDS 78.3KB -> 2 blocks/CU.
__global__ __launch_bounds__(256, 2) void attn_kernel(
    const f16* __restrict__ Qp, const f16* __restrict__ Kp,
    const f16* __restrict__ Vp, f16* __restrict__ AO)
{
    __shared__ __align__(128) f16 Kl[2][64 * 128];
    __shared__ __align__(16)  f16 Vt[128 * 76];
    __shared__ __align__(16)  f16 Pl[192 * 68];

    const int tid = threadIdx.x;
    const int lane = tid & 63, wid = tid >> 6;      // wid 0..3
    const int g = lane >> 4, l15 = lane & 15;
    const int orig = blockIdx.x;
    const int bid = (orig & 7) * 144 + (orig >> 3); // XCD-chunked remap
    const int wh = bid >> 1;                        // win*4+head
    const int half = bid & 1;
    const int win = wh >> 2, head = wh & 3;
    const int base = wh * 46080;                    // 360*128
    const int qbase = half * 192 + wid * 48;        // this wave's first q-row

    const float SC2 = 0.08838834764831845f * 1.4426950408889634f;  // scale*log2e

    #define STAGE_K(buf, kt_)                                                 \
        {                                                                     \
            _Pragma("unroll")                                                 \
            for (int it = 0; it < 4; ++it) {                                  \
                int chunk = it * 256 + tid;                                   \
                int krow = chunk >> 4, c = chunk & 15;                        \
                int sc_ = c ^ (krow & 7);                                     \
                async_copy16(&Kl[buf][chunk * 8],                             \
                    Kp + base + (size_t)((kt_) * 64 + krow) * 128 + sc_ * 8); \
            }                                                                 \
        }

    f16x8 qf[3][4];
    #pragma unroll
    for (int qi = 0; qi < 3; ++qi)
        #pragma unroll
        for (int c4 = 0; c4 < 4; ++c4)
            qf[qi][c4] = *(const f16x8*)(Qp + base + (qbase + qi * 16 + l15) * 128 + c4 * 32 + g * 8);

    STAGE_K(0, 0);

    f32x4 o[3][8] = {};
    float l_r[3] = { 0.f, 0.f, 0.f };

    for (int kt = 0; kt < 6; ++kt) {
        const int cb = kt & 1;
        // --- stage V tile transposed: [ch][k], zero-fill k >= 360, 256 thr
        #pragma unroll
        for (int it = 0; it < 2; ++it) {
            int i2 = it * 256 + tid;
            int kb = i2 >> 6;
            int chp = (i2 & 63) * 2;
            const u32* Vb = (const u32*)(Vp + base);
            u32 d[8];
            #pragma unroll
            for (int i = 0; i < 8; ++i) {
                int kg = kt * 64 + kb * 8 + i;
                d[i] = (kg < 360) ? Vb[kg * 64 + (chp >> 1)] : 0u;
            }
            u32x4 lo, hi;
            #pragma unroll
            for (int jj = 0; jj < 4; ++jj) {
                lo[jj] = (d[2 * jj] & 0xffffu) | (d[2 * jj + 1] << 16);
                hi[jj] = (d[2 * jj] >> 16) | (d[2 * jj + 1] & 0xffff0000u);
            }
            *(u32x4*)&Vt[chp * 76 + kb * 8] = lo;
            *(u32x4*)&Vt[(chp + 1) * 76 + kb * 8] = hi;
        }
        // barrier A: V writes visible; K(kt) complete (older than V's
        // reg-loads which the compiler already drained).
        __syncthreads();
        // prefetch next K tile: in flight across QK + softmax + PV
        if (kt + 1 < 6) STAGE_K(cb ^ 1, kt + 1);

        // --- S^T = K · Q^T : C[k,q], lane holds col q=lane&15, rows k=g*4+j
        f32x4 sc[4][3] = {};
        __builtin_amdgcn_s_setprio(1);
        #pragma unroll
        for (int c4 = 0; c4 < 4; ++c4) {
            f16x8 ka[4];
            #pragma unroll
            for (int kf = 0; kf < 4; ++kf) {
                int row = kf * 16 + l15;
                int sl = (c4 * 4 + g) ^ (row & 7);
                ka[kf] = *(const f16x8*)&Kl[cb][row * 128 + sl * 8];
            }
            #pragma unroll
            for (int kf = 0; kf < 4; ++kf)
                #pragma unroll
                for (int qi = 0; qi < 3; ++qi)
                    sc[kf][qi] = MFMA16(ka[kf], qf[qi][c4], sc[kf][qi]);
        }
        __builtin_amdgcn_s_setprio(0);
        if (kt == 5) {
            #pragma unroll
            for (int kf = 0; kf < 4; ++kf)
                #pragma unroll
                for (int j = 0; j < 4; ++j)
                    if (320 + kf * 16 + g * 4 + j >= 360) {
                        #pragma unroll
                        for (int qi = 0; qi < 3; ++qi) sc[kf][qi][j] = -1e30f;
                    }
        }

        // --- max-free softmax: P = exp2(s*SC2); P -> LDS (rows wave-private)
        #pragma unroll
        for (int qi = 0; qi < 3; ++qi) {
            float psum = 0.f;
            #pragma unroll
            for (int kf = 0; kf < 4; ++kf) {
                f16x4 pv;
                #pragma unroll
                for (int j = 0; j < 4; ++j) {
                    float p = exp2f(sc[kf][qi][j] * SC2);
                    psum += p;
                    pv[j] = (f16)p;
                }
                *(f16x4*)&Pl[(wid * 48 + qi * 16 + l15) * 68 + kf * 16 + g * 4] = pv;
            }
            psum += __shfl_xor(psum, 16);
            psum += __shfl_xor(psum, 32);
            l_r[qi] += psum;
        }

        // --- PV: O[q,ch] += P[q,k] * V[k,ch]
        __builtin_amdgcn_s_setprio(1);
        #pragma unroll
        for (int kc = 0; kc < 2; ++kc) {
            f16x8 pa[3], vb[8];
            #pragma unroll
            for (int qi = 0; qi < 3; ++qi)
                pa[qi] = *(const f16x8*)&Pl[(wid * 48 + qi * 16 + l15) * 68 + kc * 32 + g * 8];
            #pragma unroll
            for (int chf = 0; chf < 8; ++chf)
                vb[chf] = *(const f16x8*)&Vt[(chf * 16 + l15) * 76 + kc * 32 + g * 8];
            #pragma unroll
            for (int qi = 0; qi < 3; ++qi)
                #pragma unroll
                for (int chf = 0; chf < 8; ++chf)
                    o[qi][chf] = MFMA16(pa[qi], vb[chf], o[qi][chf]);
        }
        __builtin_amdgcn_s_setprio(0);
        // barrier B: drains K(kt+1) (long since arrived) + syncs Vt reuse
        __syncthreads();
    }
    #undef STAGE_K

    // --- epilogue: normalize, un-partition, store fp16 AO[token][512]
    #pragma unroll
    for (int qi = 0; qi < 3; ++qi) {
        #pragma unroll
        for (int j = 0; j < 4; ++j) {
            float lj = __shfl(l_r[qi], g * 4 + j);
            float inv = 1.0f / lj;
            int s = qbase + qi * 16 + g * 4 + j;
            if (s < 360) {
                int t_ = s / 45, s45 = s % 45;
                int hh = (win / 12) * 5 + s45 / 9;
                int ww = (win % 12) * 9 + s45 % 9;
                int mm = t_ * 6480 + hh * 108 + ww;
                #pragma unroll
                for (int chf = 0; chf < 8; ++chf) {
                    int col = head * 128 + chf * 16 + l15;
                    AO[(size_t)mm * 512 + col] = (f16)(o[qi][chf][j] * inv);
                }
            }
        }
    }
}

// ----------------------------------------------------------- out proj ----
// 3-deep ring, BK=32, counted vmcnt(4).
__global__ __launch_bounds__(256, 3) void proj_gemm(
    const f16* __restrict__ A, const f16* __restrict__ W,
    const float* __restrict__ bias, float* __restrict__ out)
{
    __shared__ __align__(16) f16 As[3][128 * 32];
    __shared__ __align__(16) f16 Bs[3][128 * 32];
    const int tid = threadIdx.x;
    const int lane = tid & 63, wid = tid >> 6;
    const int g = lane >> 4, l15 = lane & 15;
    const int wr = wid >> 1, wc = wid & 1;

    const int orig = blockIdx.x;
    const int xcd = orig & 7;
    const int wg = (xcd < 4 ? xcd * 203 : 812 + (xcd - 4) * 202) + (orig >> 3);
    const int bcol = (wg & 3) * 128;
    const int brow = (wg >> 2) * 128;

    const f16* Abase = A + (size_t)brow * 512;
    const f16* Bbase = W + (size_t)bcol * 512;

    f32x4 acc[4][4] = {};

    #define PROJ_STAGE(buf, step)                                             \
        {                                                                     \
            const int k0_ = (step) * 32;                                      \
            _Pragma("unroll")                                                 \
            for (int rr = 0; rr < 2; ++rr) {                                  \
                int idx = rr * 256 + tid;                                     \
                int row = idx >> 2, ch = idx & 3;                             \
                int sch = ch ^ ((row >> 1) & 3);                              \
                async_copy16(&As[buf][idx * 8],                               \
                             Abase + (size_t)row * 512 + k0_ + sch * 8);      \
                async_copy16(&Bs[buf][idx * 8],                               \
                             Bbase + (size_t)row * 512 + k0_ + sch * 8);      \
            }                                                                 \
        }

    PROJ_STAGE(0, 0);
    PROJ_STAGE(1, 1);

    int cur = 0;
    for (int t = 0; t < 16; ++t) {
        if (t < 15) asm volatile("s_waitcnt vmcnt(4)" ::: "memory");
        else        asm volatile("s_waitcnt vmcnt(0)" ::: "memory");
        __builtin_amdgcn_s_barrier();
        __builtin_amdgcn_sched_barrier(0);
        if (t + 2 < 16) {
            int stg = cur + 2; if (stg >= 3) stg -= 3;
            PROJ_STAGE(stg, t + 2);
        }
        f16x8 a[4], b[4];
        #pragma unroll
        for (int m = 0; m < 4; ++m) {
            int arow = wr * 64 + m * 16 + l15;
            int sl = g ^ ((arow >> 1) & 3);
            a[m] = *(const f16x8*)&As[cur][arow * 32 + sl * 8];
        }
        #pragma unroll
        for (int n = 0; n < 4; ++n) {
            int brw = wc * 64 + n * 16 + l15;
            int sl = g ^ ((brw >> 1) & 3);
            b[n] = *(const f16x8*)&Bs[cur][brw * 32 + sl * 8];
        }
        __builtin_amdgcn_s_setprio(1);
        #pragma unroll
        for (int m = 0; m < 4; ++m)
            #pragma unroll
            for (int n = 0; n < 4; ++n)
                acc[m][n] = MFMA16(a[m], b[n], acc[m][n]);
        __builtin_amdgcn_s_setprio(0);
        __builtin_amdgcn_s_barrier();
        cur = (cur == 2) ? 0 : cur + 1;
    }
    #undef PROJ_STAGE

    #pragma unroll
    for (int m = 0; m < 4; ++m)
        #pragma unroll
        for (int j = 0; j < 4; ++j) {
            int gm = brow + wr * 64 + m * 16 + g * 4 + j;
            #pragma unroll
            for (int n = 0; n < 4; ++n) {
                int gn = bcol + wc * 64 + n * 16 + l15;
                out[(size_t)gm * 512 + gn] = acc[m][n][j] + bias[gn];
            }
        }
}

// -------------------------------------------------------------- launch ----
extern "C" void kernel_launch(void* const* d_in, const int* in_sizes, int n_in,
                              void* d_out, int out_size, void* d_ws, size_t ws_size,
                              hipStream_t stream)
{
    (void)in_sizes; (void)n_in; (void)out_size; (void)ws_size;
    const float* x  = (const float*)d_in[0];
    const float* Wq = (const float*)d_in[1];
    const float* bq = (const float*)d_in[2];
    const float* Wk = (const float*)d_in[3];
    const float* bk = (const float*)d_in[4];
    const float* Wv = (const float*)d_in[5];
    const float* bv = (const float*)d_in[6];
    const float* Wp = (const float*)d_in[7];
    const float* bp = (const float*)d_in[8];

    // workspace layout (fp16 elems): Qp/Kp/Vp [576][360][128], AO [51840][512]
    // xh (fp16 X) aliases AO: dead before attn_kernel overwrites AO.
    f16* Qp   = (f16*)d_ws;
    f16* Kp   = Qp + 26542080;
    f16* Vp   = Kp + 26542080;
    f16* AO   = Vp + 26542080;
    f16* xh   = AO;
    f16* Wqkv = AO + 26542080;
    f16* Wph  = Wqkv + 786432;
    float* bqkv = (float*)(Wph + 262144);
    int* tokmap = (int*)(bqkv + 1536);

    prep_convert<<<17265, 256, 0, stream>>>(x, xh, Wq, Wk, Wv, Wp, bq, bk, bv,
                                            Wqkv, Wph, bqkv, tokmap);
    qkv_gemm<<<4860, 256, 0, stream>>>(xh, Wqkv, bqkv, tokmap, Qp, Kp, Vp);
    attn_kernel<<<1152, 256, 0, stream>>>(Qp, Kp, Vp, AO);
    proj_gemm<<<1620, 256, 0, stream>>>(AO, Wph, bp, (float*)d_out);
}